// Round 7
// baseline (107.669 us; speedup 1.0000x reference)
//
#include <hip/hip_runtime.h>
#include <math.h>

typedef float2 cplx;
__device__ __forceinline__ cplx mk(float r, float i){ return make_float2(r, i); }

// ---------------- state layout (identical to round 6) ----------------
// 1024-amp state per wave: 16 cplx regs x 64 lanes.
// state index n (10 bits): reg r = n[6:3]
// lane bits: n7->L0, n8->L1, n2->L2, n1->L3, n0->L4, n9->L5
template<int B> struct LSH {
  static constexpr int v = (B==7)?0 : (B==8)?1 : (B==2)?2 : (B==1)?3 : (B==0)?4 : 5;
};

template<int PB>
__device__ __forceinline__ float lx(float v){
  if constexpr (PB == 7)
    return __int_as_float(__builtin_amdgcn_update_dpp(
        __float_as_int(v), __float_as_int(v), 0xB1, 0xF, 0xF, false));
  else if constexpr (PB == 8)
    return __int_as_float(__builtin_amdgcn_update_dpp(
        __float_as_int(v), __float_as_int(v), 0x4E, 0xF, 0xF, false));
  else if constexpr (PB == 2)
    return __int_as_float(__builtin_amdgcn_ds_swizzle(__float_as_int(v), 0x101F));
  else if constexpr (PB == 1)
    return __int_as_float(__builtin_amdgcn_ds_swizzle(__float_as_int(v), 0x201F));
  else if constexpr (PB == 0)
    return __int_as_float(__builtin_amdgcn_ds_swizzle(__float_as_int(v), 0x401F));
  else
    return __shfl_xor(v, 32, 64);
}

template<int PB, int CB, bool ISRX>
__device__ __forceinline__ void gate_pass(cplx* A, float c, float s, int lane)
{
  if constexpr (PB >= 3 && PB <= 6) {
    constexpr int RM = 1 << (PB - 3);
    bool cl = false;
    if constexpr (CB >= 0 && !(CB >= 3 && CB <= 6))
      cl = (lane >> LSH<CB>::v) & 1;
    #pragma unroll
    for (int r = 0; r < 16; ++r) {
      if (r & RM) continue;
      cplx a0 = A[r], a1 = A[r | RM];
      bool sw;
      if constexpr (CB < 0) sw = false;
      else if constexpr (CB >= 3 && CB <= 6) sw = (r >> (CB - 3)) & 1;
      else sw = cl;
      float i0x = sw ? a1.x : a0.x, i0y = sw ? a1.y : a0.y;
      float i1x = sw ? a0.x : a1.x, i1y = sw ? a0.y : a1.y;
      if constexpr (ISRX) {
        A[r]      = mk(fmaf(s, i1y, c*i0x), fmaf(-s, i1x, c*i0y));
        A[r | RM] = mk(fmaf(s, i0y, c*i1x), fmaf(-s, i0x, c*i1y));
      } else {
        A[r]      = mk(fmaf(-s, i1x, c*i0x), fmaf(-s, i1y, c*i0y));
        A[r | RM] = mk(fmaf( s, i0x, c*i1x), fmaf( s, i0y, c*i1y));
      }
    }
  } else {
    const int mybit = (lane >> LSH<PB>::v) & 1;
    const float ssy = mybit ? s : -s;
    #pragma unroll
    for (int r = 0; r < 16; ++r) {
      float px = lx<PB>(A[r].x);
      float py = lx<PB>(A[r].y);
      bool sw = false;
      if constexpr (CB >= 3 && CB <= 6) sw = (r >> (CB - 3)) & 1;
      float ox = A[r].x, oy = A[r].y;
      float ux = sw ? px : ox, uy = sw ? py : oy;
      float vx = sw ? ox : px, vy = sw ? oy : py;
      if constexpr (ISRX) A[r] = mk(fmaf(s, vy, c*ux), fmaf(-s, vx, c*uy));
      else                A[r] = mk(fmaf(ssy, vx, c*ux), fmaf(ssy, vy, c*uy));
    }
  }
}

template<int LO>
__device__ __forceinline__ void iter_reg(cplx* A, int lane,
    float c0,float s0,float c1,float s1,float c2,float s2,
    float cx,float sx,float c4,float s4)
{
  gate_pass<LO+4, -1,   false>(A, c0, s0, lane);
  gate_pass<LO+1, LO+4, false>(A, c1, s1, lane);
  gate_pass<LO+3, -1,   false>(A, c2, s2, lane);
  gate_pass<LO,   LO+3, true >(A, cx, sx, lane);
  gate_pass<LO+3, LO+1, true >(A, c4, s4, lane);
}

__global__ __launch_bounds__(256) void sim_kernel(
    const float* __restrict__ x, const float* __restrict__ kp,
    float* __restrict__ pacc,   // 2048 rows x 12 floats
    int nphase, int niter)      // 2, 6 (runtime: prevents unrolling)
{
  __shared__ __align__(16) float lds[8320];

  const int tid = threadIdx.x, wv = tid >> 6, lane = tid & 63;
  const int gw = blockIdx.x * 4 + wv;
  const int pair = gw >> 6;
  const int chunk = gw & 63;
  const int b = pair & 15, k = pair >> 4;

  cplx*  P    = (cplx*)&lds[wv * 2048];
  float* angw = &lds[8192 + wv * 32];

  // ---- avgpool -> (cos,sin) half-angles ----
  {
    int a = lane >> 2, q = lane & 3;
    int ii = a >> 2, jj = a & 3;
    const float* xb = x + b*784 + ii*7*28 + jj*7;
    float s = 0.f;
    for (int e = q; e < 49; e += 4) s += xb[(e/7)*28 + (e%7)];
    s += __shfl_xor(s, 1, 64);
    s += __shfl_xor(s, 2, 64);
    float ang = s * (1.0f/49.0f) * 0.5f;
    if (q == 0){ angw[a*2] = cosf(ang); angw[a*2+1] = sinf(ang); }
  }

  const float* p5 = kp + k*5;
  float hc0 = cosf(p5[0]*0.5f), hs0 = sinf(p5[0]*0.5f);
  float hc1 = cosf(p5[1]*0.5f), hs1 = sinf(p5[1]*0.5f);
  float hc2 = cosf(p5[2]*0.5f), hs2 = sinf(p5[2]*0.5f);
  float hcx = cosf(p5[3]*0.5f), hsx = sinf(p5[3]*0.5f);
  float hc4 = cosf(p5[4]*0.5f), hs4 = sinf(p5[4]*0.5f);

  __threadfence_block();

  cplx A[16];

  // ---- stage-1 init: product state over wires 0..9 ----
  {
    float lp = 1.f;
    lp *= ((lane>>5)&1) ? angw[1]  : angw[0];
    lp *= ((lane>>1)&1) ? angw[3]  : angw[2];
    lp *= ( lane    &1) ? angw[5]  : angw[4];
    lp *= ((lane>>2)&1) ? angw[15] : angw[14];
    lp *= ((lane>>3)&1) ? angw[17] : angw[16];
    lp *= ((lane>>4)&1) ? angw[19] : angw[18];
    float c3 = angw[6],  s3 = angw[7];
    float c4w= angw[8],  s4w= angw[9];
    float c5 = angw[10], s5 = angw[11];
    float c6 = angw[12], s6 = angw[13];
    #pragma unroll
    for (int r = 0; r < 16; ++r){
      float rp = ((r&8)? s3:c3) * ((r&4)? s4w:c4w) * ((r&2)? s5:c5) * ((r&1)? s6:c6);
      A[r] = mk(lp * rp, 0.f);
    }
  }

  // ---- main loop: one code instance of the 6-iteration block, run twice ----
  #pragma unroll 1
  for (int ph = 0; ph < nphase; ++ph){
    #pragma unroll 1
    for (int it = 0; it < niter; ++it){
      switch(it){
        case 0: iter_reg<5>(A,lane,hc0,hs0,hc1,hs1,hc2,hs2,hcx,hsx,hc4,hs4); break;
        case 1: iter_reg<4>(A,lane,hc0,hs0,hc1,hs1,hc2,hs2,hcx,hsx,hc4,hs4); break;
        case 2: iter_reg<3>(A,lane,hc0,hs0,hc1,hs1,hc2,hs2,hcx,hsx,hc4,hs4); break;
        case 3: iter_reg<2>(A,lane,hc0,hs0,hc1,hs1,hc2,hs2,hcx,hsx,hc4,hs4); break;
        case 4: iter_reg<1>(A,lane,hc0,hs0,hc1,hs1,hc2,hs2,hcx,hsx,hc4,hs4); break;
        default: iter_reg<0>(A,lane,hc0,hs0,hc1,hs1,hc2,hs2,hcx,hsx,hc4,hs4); break;
      }
    }
    if (ph == 0){
      // ---- transition: dump Psi, gather window, expand (verbatim round 6) ----
      #pragma unroll
      for (int r = 0; r < 16; ++r) P[(r << 6) | lane] = A[r];
      __threadfence_block();
      int jc = (((lane>>5)&1) << 2) | (((lane>>1)&1) << 1) | (lane & 1);
      int h0 = (chunk << 4) | (jc << 1);
      int r0_ = (h0 >> 3) & 15;
      int l0_ = ((h0>>7)&1) | (((h0>>8)&1)<<1) | (((h0>>2)&1)<<2)
              | (((h0>>1)&1)<<3) | ((h0&1)<<4) | (((h0>>9)&1)<<5);
      cplx ps0 = P[(r0_ << 6) | l0_];
      cplx ps1 = P[(r0_ << 6) | l0_ | 16];
      float c10 = angw[20], s10 = angw[21];
      float c11 = angw[22], s11 = angw[23];
      float c12 = angw[24], s12 = angw[25];
      float preL = 1.f;
      preL *= ((lane>>2)&1) ? angw[27] : angw[26];
      preL *= ((lane>>3)&1) ? angw[29] : angw[28];
      preL *= ((lane>>4)&1) ? angw[31] : angw[30];
      #pragma unroll
      for (int r = 0; r < 16; ++r){
        float f = preL * (((r&4)? s10:c10) * ((r&2)? s11:c11) * ((r&1)? s12:c12));
        cplx v = (r & 8) ? ps1 : ps0;
        A[r] = mk(v.x * f, v.y * f);
      }
    }
  }

  // ---- measurement: runtime loop over the 12 wires (small code) ----
  {
    int idx_hi = (chunk << 10)
      | (((lane>>5)&1) << 9) | (((lane>>1)&1) << 8) | ((lane & 1) << 7)
      | (((lane>>2)&1) << 2) | (((lane>>3)&1) << 1) | ((lane>>4)&1);
    float p[16];
    #pragma unroll
    for (int r = 0; r < 16; ++r) p[r] = A[r].x*A[r].x + A[r].y*A[r].y;
    #pragma unroll 1
    for (int w = 0; w < 12; ++w){
      int m = 27 << (11 - w);
      float s = 0.f;
      #pragma unroll
      for (int r = 0; r < 16; ++r)
        s += (__popc((r << 3) & m) & 1) ? -p[r] : p[r];
      s = (__popc(idx_hi & m) & 1) ? -s : s;
      s += lx<7>(s);
      s += lx<8>(s);
      s += lx<2>(s);
      s += lx<1>(s);
      s += lx<0>(s);
      s += __shfl_xor(s, 32, 64);
      if (lane == 0) pacc[gw*12 + w] = s;
    }
  }
}

__global__ __launch_bounds__(256) void mlp_kernel(
    const float* __restrict__ pacc,
    const float* __restrict__ w1, const float* __restrict__ b1,
    const float* __restrict__ w2, const float* __restrict__ b2,
    const float* __restrict__ w3, const float* __restrict__ b3,
    float* __restrict__ out)
{
  __shared__ float feats[16*24];
  __shared__ float h1[16*128];
  __shared__ float h2[16*64];
  int tid = threadIdx.x;

  {
    int pr = tid >> 3, part = tid & 7;
    float sm[12];
    #pragma unroll
    for (int w = 0; w < 12; ++w) sm[w] = 0.f;
    for (int c = part; c < 64; c += 8){
      const float4* row = (const float4*)(pacc + (pr*64 + c)*12);
      float4 r0 = row[0], r1 = row[1], r2 = row[2];
      sm[0]+=r0.x; sm[1]+=r0.y; sm[2] +=r0.z; sm[3] +=r0.w;
      sm[4]+=r1.x; sm[5]+=r1.y; sm[6] +=r1.z; sm[7] +=r1.w;
      sm[8]+=r2.x; sm[9]+=r2.y; sm[10]+=r2.z; sm[11]+=r2.w;
    }
    #pragma unroll
    for (int m = 1; m < 8; m <<= 1)
      #pragma unroll
      for (int w = 0; w < 12; ++w)
        sm[w] += __shfl_xor(sm[w], m, 64);
    if (part == 0){
      int bb = pr & 15, kk = pr >> 4;
      #pragma unroll
      for (int w = 0; w < 12; ++w)
        feats[bb*24 + kk*12 + w] = sm[w];
    }
  }
  __syncthreads();

  for (int e = tid; e < 2048; e += 256){
    int bb = e >> 7, j = e & 127;
    const float4* wr = (const float4*)(w1 + j*24);
    const float4* fr = (const float4*)(feats + bb*24);
    float s = b1[j];
    #pragma unroll
    for (int q = 0; q < 6; ++q){
      float4 a = fr[q], w4 = wr[q];
      s += a.x*w4.x + a.y*w4.y + a.z*w4.z + a.w*w4.w;
    }
    h1[e] = fmaxf(s, 0.f);
  }
  __syncthreads();
  for (int e = tid; e < 1024; e += 256){
    int bb = e >> 6, j = e & 63;
    const float4* wr = (const float4*)(w2 + j*128);
    const float4* hr = (const float4*)(h1 + bb*128);
    float s = b2[j];
    #pragma unroll
    for (int q = 0; q < 32; ++q){
      float4 a = hr[q], w4 = wr[q];
      s += a.x*w4.x + a.y*w4.y + a.z*w4.z + a.w*w4.w;
    }
    h2[e] = fmaxf(s, 0.f);
  }
  __syncthreads();
  if (tid < 64){
    int bb = tid >> 2, j = tid & 3;
    const float4* wr = (const float4*)(w3 + j*64);
    const float4* hr = (const float4*)(h2 + bb*64);
    float s = b3[j];
    #pragma unroll
    for (int q = 0; q < 16; ++q){
      float4 a = hr[q], w4 = wr[q];
      s += a.x*w4.x + a.y*w4.y + a.z*w4.z + a.w*w4.w;
    }
    out[tid] = s;
  }
}

extern "C" void kernel_launch(void* const* d_in, const int* in_sizes, int n_in,
                              void* d_out, int out_size, void* d_ws, size_t ws_size,
                              hipStream_t stream) {
  const float* x  = (const float*)d_in[0];
  const float* kp = (const float*)d_in[1];
  const float* w1 = (const float*)d_in[2];
  const float* b1 = (const float*)d_in[3];
  const float* w2 = (const float*)d_in[4];
  const float* b2 = (const float*)d_in[5];
  const float* w3 = (const float*)d_in[6];
  const float* b3 = (const float*)d_in[7];
  float* out  = (float*)d_out;
  float* pacc = (float*)d_ws;   // 2048*12 floats

  sim_kernel<<<512, 256, 0, stream>>>(x, kp, pacc, 2, 6);
  mlp_kernel<<<1, 256, 0, stream>>>(pacc, w1, b1, w2, b2, w3, b3, out);
}